// Round 1
// baseline (482.957 us; speedup 1.0000x reference)
//
#include <hip/hip_runtime.h>

typedef unsigned int uint32;
typedef unsigned short ushort16;

#define DI __device__ __forceinline__

// ---- constants -------------------------------------------------------------
// B=2048, N_src=1, N_ngh=128, D_MODEL=FEAT=256, H=4, D_K=64, TEMP=8
#define BATCH 2048
#define NN    128
#define DM    256
#define NH    4
#define DK    64

// bf16 (as ushort) -> f32
DI float bf2f(ushort16 h) { return __uint_as_float(((uint32)h) << 16); }

// f32 -> bf16 (round to nearest even)
DI ushort16 f2bf(float f) {
    uint32 u = __float_as_uint(f);
    uint32 r = u + 0x7fffu + ((u >> 16) & 1u);
    return (ushort16)(r >> 16);
}

// unpack 8 bf16 (as uint4) -> 8 f32
DI void unpack8(const uint4 v, float f[8]) {
    f[0] = __uint_as_float(v.x << 16);
    f[1] = __uint_as_float(v.x & 0xffff0000u);
    f[2] = __uint_as_float(v.y << 16);
    f[3] = __uint_as_float(v.y & 0xffff0000u);
    f[4] = __uint_as_float(v.z << 16);
    f[5] = __uint_as_float(v.z & 0xffff0000u);
    f[6] = __uint_as_float(v.w << 16);
    f[7] = __uint_as_float(v.w & 0xffff0000u);
}

DI float dot8(const float* a, const float f[8], float acc) {
    acc = fmaf(a[0], f[0], acc);
    acc = fmaf(a[1], f[1], acc);
    acc = fmaf(a[2], f[2], acc);
    acc = fmaf(a[3], f[3], acc);
    acc = fmaf(a[4], f[4], acc);
    acc = fmaf(a[5], f[5], acc);
    acc = fmaf(a[6], f[6], acc);
    acc = fmaf(a[7], f[7], acc);
    return acc;
}

// ---- weight layout in d_ws bf16 area (element offsets) ---------------------
// NOTE: WOFF_KS region now holds wks TRANSPOSED: [c][r] = wks[r*256+c]
#define WOFF_QS  0
#define WOFF_KS  65536
#define WOFF_VS  131072
#define WOFF_FC  196608
#define WOFF_FC1 262144
#define WOFF_FC2 393216
// total 458752 bf16 elements

// ---- kernel 0: convert all weight matrices to bf16 in d_ws -----------------
// grid 448, block 256; each block converts 1024 elements.
// wks is stored transposed so qu stage-2 can do vectorized row loads.
__global__ __launch_bounds__(256) void prep_kernel(
    const float* __restrict__ wqs, const float* __restrict__ wks,
    const float* __restrict__ wvs, const float* __restrict__ fcw,
    const float* __restrict__ fc1w, const float* __restrict__ fc2w,
    ushort16* __restrict__ out)
{
    const int bid = blockIdx.x;
    const int t   = threadIdx.x;
    if (bid >= 64 && bid < 128) {
        // wks stored TRANSPOSED: out[WOFF_KS + c*256 + r] = bf16(wks[r*256+c])
        int base = (bid - 64) * 1024 + t * 4;
        float4 v = *(const float4*)(wks + base);
        int r = base >> 8, c = base & 255;
        out[WOFF_KS + (size_t)(c + 0) * 256 + r] = f2bf(v.x);
        out[WOFF_KS + (size_t)(c + 1) * 256 + r] = f2bf(v.y);
        out[WOFF_KS + (size_t)(c + 2) * 256 + r] = f2bf(v.z);
        out[WOFF_KS + (size_t)(c + 3) * 256 + r] = f2bf(v.w);
        return;
    }
    const float* srcp; size_t soff, doff;
    if (bid < 64)       { srcp = wqs;  soff = (size_t)bid * 1024;         doff = WOFF_QS;  }
    else if (bid < 192) { srcp = wvs;  soff = (size_t)(bid - 128) * 1024; doff = WOFF_VS;  }
    else if (bid < 256) { srcp = fcw;  soff = (size_t)(bid - 192) * 1024; doff = WOFF_FC;  }
    else if (bid < 384) { srcp = fc1w; soff = (size_t)(bid - 256) * 1024; doff = WOFF_FC1; }
    else                { srcp = fc2w; soff = (size_t)(bid - 384) * 1024; doff = WOFF_FC2; }
    float4 v = *(const float4*)(srcp + soff + t * 4);
    uint2 pk;
    pk.x = (uint32)f2bf(v.x) | ((uint32)f2bf(v.y) << 16);
    pk.y = (uint32)f2bf(v.z) | ((uint32)f2bf(v.w) << 16);
    *(uint2*)(out + doff + soff + t * 4) = pk;
}

// ---- kernel 1: u[b,h,:] = (src[b] @ w_qs^T)[h,:] @ w_ks_h  (scaled 1/TEMP) --
// grid 512, block 256, 4 batch rows per block (2 blocks/CU for latency hiding)
__global__ __launch_bounds__(256) void qu_kernel(
    const float* __restrict__ src, const ushort16* __restrict__ wbf,
    float* __restrict__ u)
{
    __shared__ float sS[4][DM];   // src rows
    __shared__ float sQ[4][DM];   // q rows
    const int t  = threadIdx.x;
    const int b0 = blockIdx.x * 4;

    #pragma unroll
    for (int r = 0; r < 4; ++r) sS[r][t] = src[(size_t)(b0 + r) * DM + t];
    __syncthreads();

    // q[r][t] = sum_c sS[r][c] * wqs[t*256+c]
    {
        float acc[4] = {0.f,0.f,0.f,0.f};
        const ushort16* wrow = wbf + WOFF_QS + (size_t)t * DM;
        #pragma unroll 2
        for (int kc = 0; kc < DM; kc += 8) {
            uint4 w8 = *(const uint4*)(wrow + kc);
            float wf[8]; unpack8(w8, wf);
            #pragma unroll
            for (int r = 0; r < 4; ++r) acc[r] = dot8(&sS[r][kc], wf, acc[r]);
        }
        #pragma unroll
        for (int r = 0; r < 4; ++r) sQ[r][t] = acc[r];
    }
    __syncthreads();

    // u[r][h][t] = sum_d sQ[r][h*64+d] * wksT[t*256 + h*64+d]
    const ushort16* wr2 = wbf + WOFF_KS + (size_t)t * DM;
    #pragma unroll
    for (int h = 0; h < NH; ++h) {
        float ua[4] = {0.f,0.f,0.f,0.f};
        #pragma unroll 2
        for (int dc = 0; dc < DK; dc += 8) {
            uint4 w8 = *(const uint4*)(wr2 + h * DK + dc);
            float wf[8]; unpack8(w8, wf);
            #pragma unroll
            for (int r = 0; r < 4; ++r) ua[r] = dot8(&sQ[r][h * DK + dc], wf, ua[r]);
        }
        #pragma unroll
        for (int r = 0; r < 4; ++r)
            u[(size_t)(b0 + r) * (NH * DM) + h * DM + t] = ua[r] * 0.125f;
    }
}

// ---- kernel 2: per-b attention: scores -> mask -> softmax -> pooled c ------
// grid 2048, block 256. seq read DIRECTLY from global (f32), twice:
// scores pass (coalesced row-shared reads) + pooling pass (16B/lane coalesced,
// second pass hits L2/L3). LDS only 18.4 KB -> 8 blocks/CU (32 waves/CU).
#define U_STRIDE 264   // u rows padded: banks {0,8,16,24} across h -> no conflict

__global__ __launch_bounds__(256) void attn_kernel(
    const float* __restrict__ seq, const int* __restrict__ mask,
    const float* __restrict__ u, float* __restrict__ c,
    float* __restrict__ attn_out)
{
    __shared__ float sred[4096];      // u rows (scores) -> c partials (pooling)
    __shared__ float sattn[NN * NH];  // [n][h]: n*4+h

    const int t = threadIdx.x;
    const int b = blockIdx.x;
    const float* sp = seq + (size_t)b * (NN * DM);

    // load u[b] (1024 f32) into padded rows of sred
    #pragma unroll
    for (int i = 0; i < 4; ++i)
        sred[i * U_STRIDE + t] = u[(size_t)b * 1024 + i * 256 + t];
    __syncthreads();

    // scores: 4-lane groups share a seq row (global broadcast); h = t&3.
    {
        const int h  = t & 3;
        const int n0 = t >> 2;            // 0..63
        const float* uh = &sred[h * U_STRIDE];
        const float* r0 = sp + n0 * DM;
        const float* r1 = r0 + 64 * DM;
        float s0 = 0.f, s1 = 0.f;
        #pragma unroll 2
        for (int kc = 0; kc < DM; kc += 8) {
            float4 u0 = *(const float4*)(uh + kc);
            float4 u1 = *(const float4*)(uh + kc + 4);
            float4 a0 = *(const float4*)(r0 + kc);
            float4 a1 = *(const float4*)(r0 + kc + 4);
            float4 d0 = *(const float4*)(r1 + kc);
            float4 d1 = *(const float4*)(r1 + kc + 4);
            s0 = fmaf(u0.x, a0.x, s0); s0 = fmaf(u0.y, a0.y, s0);
            s0 = fmaf(u0.z, a0.z, s0); s0 = fmaf(u0.w, a0.w, s0);
            s0 = fmaf(u1.x, a1.x, s0); s0 = fmaf(u1.y, a1.y, s0);
            s0 = fmaf(u1.z, a1.z, s0); s0 = fmaf(u1.w, a1.w, s0);
            s1 = fmaf(u0.x, d0.x, s1); s1 = fmaf(u0.y, d0.y, s1);
            s1 = fmaf(u0.z, d0.z, s1); s1 = fmaf(u0.w, d0.w, s1);
            s1 = fmaf(u1.x, d1.x, s1); s1 = fmaf(u1.y, d1.y, s1);
            s1 = fmaf(u1.z, d1.z, s1); s1 = fmaf(u1.w, d1.w, s1);
        }
        // mask rows: (4b+h) mod 2048  (reference's head-major tiling)
        int mr = (4 * b + h) & (BATCH - 1);
        if (mask[(size_t)mr * NN + n0] != 0)      s0 = -1e10f;
        if (mask[(size_t)mr * NN + n0 + 64] != 0) s1 = -1e10f;
        sattn[n0 * 4 + h]        = s0;
        sattn[(n0 + 64) * 4 + h] = s1;
    }
    __syncthreads();

    // softmax: wave w handles head w; lanes hold n=l and n=l+64
    {
        const int w = t >> 6, l = t & 63;
        float x0 = sattn[l * 4 + w], x1 = sattn[(l + 64) * 4 + w];
        float mx = fmaxf(x0, x1);
        #pragma unroll
        for (int o = 32; o > 0; o >>= 1) mx = fmaxf(mx, __shfl_xor(mx, o, 64));
        float e0 = __expf(x0 - mx), e1 = __expf(x1 - mx);
        float sm = e0 + e1;
        #pragma unroll
        for (int o = 32; o > 0; o >>= 1) sm += __shfl_xor(sm, o, 64);
        float inv = 1.f / sm;
        float a0 = e0 * inv, a1 = e1 * inv;
        sattn[l * 4 + w]        = a0;
        sattn[(l + 64) * 4 + w] = a1;
        attn_out[(size_t)b * (NH * NN) + w * NN + l]      = a0;
        attn_out[(size_t)b * (NH * NN) + w * NN + l + 64] = a1;
    }
    __syncthreads();

    // pooled c[h][j] = sum_n attn[n][h] * seq[n][j]
    // wave q owns n in [q*32, q*32+32); lane owns a col quad (16B coalesced)
    {
        const int q  = t >> 6;
        const int j4 = (t & 63) * 4;
        float cc[4][4];
        #pragma unroll
        for (int h2 = 0; h2 < 4; ++h2) {
            cc[h2][0] = 0.f; cc[h2][1] = 0.f; cc[h2][2] = 0.f; cc[h2][3] = 0.f;
        }
        #pragma unroll 2
        for (int i = 0; i < 32; ++i) {
            const int n = q * 32 + i;
            float4 sv = *(const float4*)(sp + n * DM + j4);
            float4 at = *(const float4*)&sattn[n * 4];   // wave-uniform broadcast
            cc[0][0] = fmaf(at.x, sv.x, cc[0][0]); cc[0][1] = fmaf(at.x, sv.y, cc[0][1]);
            cc[0][2] = fmaf(at.x, sv.z, cc[0][2]); cc[0][3] = fmaf(at.x, sv.w, cc[0][3]);
            cc[1][0] = fmaf(at.y, sv.x, cc[1][0]); cc[1][1] = fmaf(at.y, sv.y, cc[1][1]);
            cc[1][2] = fmaf(at.y, sv.z, cc[1][2]); cc[1][3] = fmaf(at.y, sv.w, cc[1][3]);
            cc[2][0] = fmaf(at.z, sv.x, cc[2][0]); cc[2][1] = fmaf(at.z, sv.y, cc[2][1]);
            cc[2][2] = fmaf(at.z, sv.z, cc[2][2]); cc[2][3] = fmaf(at.z, sv.w, cc[2][3]);
            cc[3][0] = fmaf(at.w, sv.x, cc[3][0]); cc[3][1] = fmaf(at.w, sv.y, cc[3][1]);
            cc[3][2] = fmaf(at.w, sv.z, cc[3][2]); cc[3][3] = fmaf(at.w, sv.w, cc[3][3]);
        }
        // u region of sred is dead (last read was pre-softmax, 2 barriers ago)
        #pragma unroll
        for (int h2 = 0; h2 < 4; ++h2)
            *(float4*)&sred[q * 1024 + h2 * 256 + j4] =
                make_float4(cc[h2][0], cc[h2][1], cc[h2][2], cc[h2][3]);
    }
    __syncthreads();
    #pragma unroll
    for (int h2 = 0; h2 < 4; ++h2)
        c[(size_t)b * 1024 + h2 * 256 + t] =
            sred[h2 * 256 + t] + sred[1024 + h2 * 256 + t] +
            sred[2048 + h2 * 256 + t] + sred[3072 + h2 * 256 + t];
}

// ---- kernel 3: v-proj + fc + residual + LN + fc1(relu) + fc2 ---------------
// grid 512, block 256, 4 rows per block (2 blocks/CU); bf16 weights
__global__ __launch_bounds__(256) void mlp_kernel(
    const float* __restrict__ c, const float* __restrict__ src,
    const ushort16* __restrict__ wbf,
    const float* __restrict__ fcb, const float* __restrict__ lng,
    const float* __restrict__ lnb, const float* __restrict__ fc1b,
    const float* __restrict__ fc2b, float* __restrict__ zout)
{
    __shared__ float sC[4][1024];   // pooled c rows (16 KB)
    __shared__ float sA[4][256];    // attention out rows
    __shared__ float sX[4][256];    // normalized x
    __shared__ float sS[4][256];    // src rows
    __shared__ float sH[4][256];    // relu(fc1) rows
    __shared__ float sRed[4][4][2]; // [wave][row][{sum, sumsq}]

    const int t  = threadIdx.x;
    const int b0 = blockIdx.x * 4;
    const int h  = t >> 6;          // head for stage A (uniform per wave)

    #pragma unroll
    for (int i = 0; i < 4; ++i)
        *(float4*)&sC[i][t * 4] = *(const float4*)&c[(size_t)(b0 + i) * 1024 + t * 4];
    #pragma unroll
    for (int r = 0; r < 4; ++r) sS[r][t] = src[(size_t)(b0 + r) * DM + t];
    __syncthreads();

    // stage A: out_attn[r][t] = dot(c[r][h*256 + :], wvs[t*256 + :])
    {
        float acc[4] = {0.f,0.f,0.f,0.f};
        const ushort16* wr = wbf + WOFF_VS + (size_t)t * DM;
        #pragma unroll 2
        for (int kc = 0; kc < DM; kc += 8) {
            uint4 w8 = *(const uint4*)(wr + kc);
            float wf[8]; unpack8(w8, wf);
            #pragma unroll
            for (int r = 0; r < 4; ++r) acc[r] = dot8(&sC[r][h * 256 + kc], wf, acc[r]);
        }
        #pragma unroll
        for (int r = 0; r < 4; ++r) sA[r][t] = acc[r];
    }
    __syncthreads();

    // stage B: x = out_attn @ fcw^T + fcb + src ; then LayerNorm
    float xv[4];
    {
        float acc[4] = {0.f,0.f,0.f,0.f};
        const ushort16* wr = wbf + WOFF_FC + (size_t)t * DM;
        #pragma unroll 2
        for (int kc = 0; kc < DM; kc += 8) {
            uint4 w8 = *(const uint4*)(wr + kc);
            float wf[8]; unpack8(w8, wf);
            #pragma unroll
            for (int r = 0; r < 4; ++r) acc[r] = dot8(&sA[r][kc], wf, acc[r]);
        }
        float bb = fcb[t];
        #pragma unroll
        for (int r = 0; r < 4; ++r) xv[r] = acc[r] + bb + sS[r][t];
    }
    {
        const int w = t >> 6, l = t & 63;
        #pragma unroll
        for (int r = 0; r < 4; ++r) {
            float vs = xv[r], vq = xv[r] * xv[r];
            #pragma unroll
            for (int o = 32; o > 0; o >>= 1) {
                vs += __shfl_xor(vs, o, 64);
                vq += __shfl_xor(vq, o, 64);
            }
            if (l == 0) { sRed[w][r][0] = vs; sRed[w][r][1] = vq; }
        }
        __syncthreads();
        float g = lng[t], bb = lnb[t];
        #pragma unroll
        for (int r = 0; r < 4; ++r) {
            float S = sRed[0][r][0] + sRed[1][r][0] + sRed[2][r][0] + sRed[3][r][0];
            float Q = sRed[0][r][1] + sRed[1][r][1] + sRed[2][r][1] + sRed[3][r][1];
            float mu  = S * (1.f / 256.f);
            float var = Q * (1.f / 256.f) - mu * mu;
            float rs  = rsqrtf(var + 1e-5f);
            sX[r][t] = (xv[r] - mu) * rs * g + bb;
        }
    }
    __syncthreads();

    // stage C: h1 = relu([x | src] @ fc1w^T + fc1b)
    {
        float acc[4] = {0.f,0.f,0.f,0.f};
        const ushort16* wr = wbf + WOFF_FC1 + (size_t)t * 512;
        #pragma unroll 2
        for (int kc = 0; kc < 256; kc += 8) {
            uint4 w8 = *(const uint4*)(wr + kc);
            float wf[8]; unpack8(w8, wf);
            #pragma unroll
            for (int r = 0; r < 4; ++r) acc[r] = dot8(&sX[r][kc], wf, acc[r]);
        }
        #pragma unroll 2
        for (int kc = 0; kc < 256; kc += 8) {
            uint4 w8 = *(const uint4*)(wr + 256 + kc);
            float wf[8]; unpack8(w8, wf);
            #pragma unroll
            for (int r = 0; r < 4; ++r) acc[r] = dot8(&sS[r][kc], wf, acc[r]);
        }
        float bb = fc1b[t];
        #pragma unroll
        for (int r = 0; r < 4; ++r) sH[r][t] = fmaxf(acc[r] + bb, 0.f);
    }
    __syncthreads();

    // stage D: z = h1 @ fc2w^T + fc2b
    {
        float acc[4] = {0.f,0.f,0.f,0.f};
        const ushort16* wr = wbf + WOFF_FC2 + (size_t)t * DM;
        #pragma unroll 2
        for (int kc = 0; kc < DM; kc += 8) {
            uint4 w8 = *(const uint4*)(wr + kc);
            float wf[8]; unpack8(w8, wf);
            #pragma unroll
            for (int r = 0; r < 4; ++r) acc[r] = dot8(&sH[r][kc], wf, acc[r]);
        }
        float bb = fc2b[t];
        #pragma unroll
        for (int r = 0; r < 4; ++r)
            zout[(size_t)(b0 + r) * DM + t] = acc[r] + bb;
    }
}

// ---- launch ----------------------------------------------------------------
extern "C" void kernel_launch(void* const* d_in, const int* in_sizes, int n_in,
                              void* d_out, int out_size, void* d_ws, size_t ws_size,
                              hipStream_t stream)
{
    const float* src  = (const float*)d_in[0];
    const float* seq  = (const float*)d_in[1];
    const int*   mask = (const int*)d_in[2];
    const float* wqs  = (const float*)d_in[3];
    const float* wks  = (const float*)d_in[4];
    const float* wvs  = (const float*)d_in[5];
    const float* fcw  = (const float*)d_in[6];
    const float* fcb  = (const float*)d_in[7];
    const float* lng  = (const float*)d_in[8];
    const float* lnb  = (const float*)d_in[9];
    const float* fc1w = (const float*)d_in[10];
    const float* fc1b = (const float*)d_in[11];
    const float* fc2w = (const float*)d_in[12];
    const float* fc2b = (const float*)d_in[13];

    float* zout     = (float*)d_out;
    float* attn_out = zout + (size_t)BATCH * DM;      // z first, then attn

    float* u = (float*)d_ws;                          // 2048*1024 f32 = 8 MB
    float* cbuf = u + (size_t)BATCH * 1024;           // 2048*1024 f32 = 8 MB
    ushort16* wbf = (ushort16*)(cbuf + (size_t)BATCH * 1024);  // 458752 bf16

    prep_kernel<<<448, 256, 0, stream>>>(wqs, wks, wvs, fcw, fc1w, fc2w, wbf);
    qu_kernel<<<512, 256, 0, stream>>>(src, wbf, u);
    attn_kernel<<<BATCH, 256, 0, stream>>>(seq, mask, u, cbuf, attn_out);
    mlp_kernel<<<512, 256, 0, stream>>>(cbuf, src, wbf, fcb, lng, lnb,
                                        fc1b, fc2b, zout);
}

// Round 2
// 465.642 us; speedup vs baseline: 1.0372x; 1.0372x over previous
//
#include <hip/hip_runtime.h>

typedef unsigned int uint32;
typedef unsigned short ushort16;

#define DI __device__ __forceinline__

// ---- constants -------------------------------------------------------------
// B=2048, N_src=1, N_ngh=128, D_MODEL=FEAT=256, H=4, D_K=64, TEMP=8
#define BATCH 2048
#define NN    128
#define DM    256
#define NH    4
#define DK    64

// async global->LDS, 16B per lane; dest = wave-uniform base + lane*16,
// source = per-lane global address (guide §5 / m97 / m173 pattern)
#define GLOAD_LDS16(g, s) \
  __builtin_amdgcn_global_load_lds( \
      (const __attribute__((address_space(1))) unsigned int*)(g), \
      (__attribute__((address_space(3))) unsigned int*)(s), 16, 0, 0)

// bf16 (as ushort) -> f32
DI float bf2f(ushort16 h) { return __uint_as_float(((uint32)h) << 16); }

// f32 -> bf16 (round to nearest even)
DI ushort16 f2bf(float f) {
    uint32 u = __float_as_uint(f);
    uint32 r = u + 0x7fffu + ((u >> 16) & 1u);
    return (ushort16)(r >> 16);
}

// unpack 8 bf16 (as uint4) -> 8 f32
DI void unpack8(const uint4 v, float f[8]) {
    f[0] = __uint_as_float(v.x << 16);
    f[1] = __uint_as_float(v.x & 0xffff0000u);
    f[2] = __uint_as_float(v.y << 16);
    f[3] = __uint_as_float(v.y & 0xffff0000u);
    f[4] = __uint_as_float(v.z << 16);
    f[5] = __uint_as_float(v.z & 0xffff0000u);
    f[6] = __uint_as_float(v.w << 16);
    f[7] = __uint_as_float(v.w & 0xffff0000u);
}

DI float dot8(const float* a, const float f[8], float acc) {
    acc = fmaf(a[0], f[0], acc);
    acc = fmaf(a[1], f[1], acc);
    acc = fmaf(a[2], f[2], acc);
    acc = fmaf(a[3], f[3], acc);
    acc = fmaf(a[4], f[4], acc);
    acc = fmaf(a[5], f[5], acc);
    acc = fmaf(a[6], f[6], acc);
    acc = fmaf(a[7], f[7], acc);
    return acc;
}

// ---- weight layout in d_ws bf16 area (element offsets) ---------------------
// WOFF_KS region holds wks TRANSPOSED: [c][r] = wks[r*256+c]
#define WOFF_QS  0
#define WOFF_KS  65536
#define WOFF_VS  131072
#define WOFF_FC  196608
#define WOFF_FC1 262144
#define WOFF_FC2 393216
// total 458752 bf16 elements

// ---- kernel 0: convert all weight matrices to bf16 in d_ws -----------------
__global__ __launch_bounds__(256) void prep_kernel(
    const float* __restrict__ wqs, const float* __restrict__ wks,
    const float* __restrict__ wvs, const float* __restrict__ fcw,
    const float* __restrict__ fc1w, const float* __restrict__ fc2w,
    ushort16* __restrict__ out)
{
    const int bid = blockIdx.x;
    const int t   = threadIdx.x;
    if (bid >= 64 && bid < 128) {
        // wks stored TRANSPOSED: out[WOFF_KS + c*256 + r] = bf16(wks[r*256+c])
        int base = (bid - 64) * 1024 + t * 4;
        float4 v = *(const float4*)(wks + base);
        int r = base >> 8, c = base & 255;
        out[WOFF_KS + (size_t)(c + 0) * 256 + r] = f2bf(v.x);
        out[WOFF_KS + (size_t)(c + 1) * 256 + r] = f2bf(v.y);
        out[WOFF_KS + (size_t)(c + 2) * 256 + r] = f2bf(v.z);
        out[WOFF_KS + (size_t)(c + 3) * 256 + r] = f2bf(v.w);
        return;
    }
    const float* srcp; size_t soff, doff;
    if (bid < 64)       { srcp = wqs;  soff = (size_t)bid * 1024;         doff = WOFF_QS;  }
    else if (bid < 192) { srcp = wvs;  soff = (size_t)(bid - 128) * 1024; doff = WOFF_VS;  }
    else if (bid < 256) { srcp = fcw;  soff = (size_t)(bid - 192) * 1024; doff = WOFF_FC;  }
    else if (bid < 384) { srcp = fc1w; soff = (size_t)(bid - 256) * 1024; doff = WOFF_FC1; }
    else                { srcp = fc2w; soff = (size_t)(bid - 384) * 1024; doff = WOFF_FC2; }
    float4 v = *(const float4*)(srcp + soff + t * 4);
    uint2 pk;
    pk.x = (uint32)f2bf(v.x) | ((uint32)f2bf(v.y) << 16);
    pk.y = (uint32)f2bf(v.z) | ((uint32)f2bf(v.w) << 16);
    *(uint2*)(out + doff + soff + t * 4) = pk;
}

// ---- kernel 1: u[b,h,:] = (src[b] @ w_qs^T)[h,:] @ w_ks_h  (scaled 1/TEMP) --
// grid 512, block 256, 4 batch rows per block (2 blocks/CU)
__global__ __launch_bounds__(256) void qu_kernel(
    const float* __restrict__ src, const ushort16* __restrict__ wbf,
    float* __restrict__ u)
{
    __shared__ float sS[4][DM];   // src rows
    __shared__ float sQ[4][DM];   // q rows
    const int t  = threadIdx.x;
    const int b0 = blockIdx.x * 4;

    #pragma unroll
    for (int r = 0; r < 4; ++r) sS[r][t] = src[(size_t)(b0 + r) * DM + t];
    __syncthreads();

    // q[r][t] = sum_c sS[r][c] * wqs[t*256+c]
    {
        float acc[4] = {0.f,0.f,0.f,0.f};
        const ushort16* wrow = wbf + WOFF_QS + (size_t)t * DM;
        #pragma unroll 2
        for (int kc = 0; kc < DM; kc += 8) {
            uint4 w8 = *(const uint4*)(wrow + kc);
            float wf[8]; unpack8(w8, wf);
            #pragma unroll
            for (int r = 0; r < 4; ++r) acc[r] = dot8(&sS[r][kc], wf, acc[r]);
        }
        #pragma unroll
        for (int r = 0; r < 4; ++r) sQ[r][t] = acc[r];
    }
    __syncthreads();

    // u[r][h][t] = sum_d sQ[r][h*64+d] * wksT[t*256 + h*64+d]
    const ushort16* wr2 = wbf + WOFF_KS + (size_t)t * DM;
    #pragma unroll
    for (int h = 0; h < NH; ++h) {
        float ua[4] = {0.f,0.f,0.f,0.f};
        #pragma unroll 2
        for (int dc = 0; dc < DK; dc += 8) {
            uint4 w8 = *(const uint4*)(wr2 + h * DK + dc);
            float wf[8]; unpack8(w8, wf);
            #pragma unroll
            for (int r = 0; r < 4; ++r) ua[r] = dot8(&sQ[r][h * DK + dc], wf, ua[r]);
        }
        #pragma unroll
        for (int r = 0; r < 4; ++r)
            u[(size_t)(b0 + r) * (NH * DM) + h * DM + t] = ua[r] * 0.125f;
    }
}

// ---- kernel 2: fused one-pass attention ------------------------------------
// grid 2048, block 512 (8 waves). Wave w owns rows [w*16, w*16+16).
// seq[b] staged ONCE to LDS as f32 via global_load_lds (async, no convert),
// 16B-chunk XOR swizzle (chunk c of row r stored at c^(r&7)) -> conflict-free
// ds_read_b128 in both the row-wise scores pass and col-wise pooling pass.
// Per-wave softmax partials (m,s,C) merged flash-style across waves.
// LDS ~135.7 KB -> 1 block/CU, waves independent until one merge barrier.
#define USTRIDE 276   // padded u row (f32): h-stride 69 chunks -> spread groups

__global__ __launch_bounds__(512) void attn_kernel(
    const float* __restrict__ seq, const int* __restrict__ mask,
    const float* __restrict__ u, float* __restrict__ c,
    float* __restrict__ attn_out)
{
    __shared__ float sq[NN * DM];        // 128 KB seq tile (swizzled rows)
    __shared__ float sU[NH * USTRIDE];   // u rows, padded
    __shared__ float sM[8][4];           // per-wave, per-head max
    __shared__ float sSg[8][4];          // per-wave, per-head sum

    const int t = threadIdx.x;
    const int b = blockIdx.x;
    const int w = t >> 6, l = t & 63;
    const int ln = l >> 2, h = l & 3;    // scores mapping: lane = ln*4+h

    // cooperative u load (1024 f32) into padded rows
    if (t < 256) {
        float4 v = *(const float4*)(u + (size_t)b * 1024 + t * 4);
        int hh = t >> 6, j = (t & 63) * 4;
        *(float4*)&sU[hh * USTRIDE + j] = v;
    }
    __syncthreads();

    // wave w async-loads its 16 rows; source pre-swizzled so linear LDS dest
    // yields chunk-swizzled layout: LDS chunk (r, cc) = global chunk (r, cc^(r&7))
    const float* sp = seq + (size_t)b * (NN * DM);
    #pragma unroll
    for (int i = 0; i < 16; ++i) {
        const int r = w * 16 + i;
        const float* ga = sp + r * DM + ((l ^ (r & 7)) << 2);
        GLOAD_LDS16(ga, &sq[r * DM]);
    }
    asm volatile("s_waitcnt vmcnt(0)" ::: "memory");
    __builtin_amdgcn_sched_barrier(0);

    // ---- scores: lane (ln,h) dots u[h] . seq[row rr] ------------------------
    const int rr = w * 16 + ln;
    float s = 0.f;
    {
        const float* urow = &sU[h * USTRIDE];
        const int rsw = rr & 7;
        #pragma unroll 8
        for (int g = 0; g < 64; ++g) {
            float4 sv = *(const float4*)&sq[rr * DM + ((g ^ rsw) << 2)];
            float4 uv = *(const float4*)&urow[g * 4];
            s = fmaf(uv.x, sv.x, s);
            s = fmaf(uv.y, sv.y, s);
            s = fmaf(uv.z, sv.z, s);
            s = fmaf(uv.w, sv.w, s);
        }
    }
    // mask: rows (4b+h) mod 2048 (reference's head-major tiling)
    {
        int mr = (4 * b + h) & (BATCH - 1);
        if (mask[(size_t)mr * NN + rr] != 0) s = -1e10f;
    }
    // per-wave per-head softmax partial (reduce over ln: lane bits 2..5)
    float m = s;
    m = fmaxf(m, __shfl_xor(m, 4));
    m = fmaxf(m, __shfl_xor(m, 8));
    m = fmaxf(m, __shfl_xor(m, 16));
    m = fmaxf(m, __shfl_xor(m, 32));
    float ev = __expf(s - m);
    float sg = ev;
    sg += __shfl_xor(sg, 4);
    sg += __shfl_xor(sg, 8);
    sg += __shfl_xor(sg, 16);
    sg += __shfl_xor(sg, 32);

    // ---- pooling: lane owns chunk col l (f32 cols l*4..l*4+3), all 4 heads --
    float cc[4][4];
    #pragma unroll
    for (int hh = 0; hh < 4; ++hh) {
        cc[hh][0] = 0.f; cc[hh][1] = 0.f; cc[hh][2] = 0.f; cc[hh][3] = 0.f;
    }
    #pragma unroll
    for (int i = 0; i < 16; ++i) {
        float e0 = __shfl(ev, i * 4 + 0);
        float e1 = __shfl(ev, i * 4 + 1);
        float e2 = __shfl(ev, i * 4 + 2);
        float e3 = __shfl(ev, i * 4 + 3);
        const int r = w * 16 + i;
        float4 sv = *(const float4*)&sq[r * DM + ((l ^ (r & 7)) << 2)];
        cc[0][0] = fmaf(e0, sv.x, cc[0][0]); cc[0][1] = fmaf(e0, sv.y, cc[0][1]);
        cc[0][2] = fmaf(e0, sv.z, cc[0][2]); cc[0][3] = fmaf(e0, sv.w, cc[0][3]);
        cc[1][0] = fmaf(e1, sv.x, cc[1][0]); cc[1][1] = fmaf(e1, sv.y, cc[1][1]);
        cc[1][2] = fmaf(e1, sv.z, cc[1][2]); cc[1][3] = fmaf(e1, sv.w, cc[1][3]);
        cc[2][0] = fmaf(e2, sv.x, cc[2][0]); cc[2][1] = fmaf(e2, sv.y, cc[2][1]);
        cc[2][2] = fmaf(e2, sv.z, cc[2][2]); cc[2][3] = fmaf(e2, sv.w, cc[2][3]);
        cc[3][0] = fmaf(e3, sv.x, cc[3][0]); cc[3][1] = fmaf(e3, sv.y, cc[3][1]);
        cc[3][2] = fmaf(e3, sv.z, cc[3][2]); cc[3][3] = fmaf(e3, sv.w, cc[3][3]);
    }

    // ---- write per-wave partials into wave's OWN dead seq slice -------------
    // wave w's merge area: f32 [w*4096, w*4096+1024) = bytes [w*16KB, +4KB)
    // (first 4KB of its own slice; safe without a barrier)
    #pragma unroll
    for (int hh = 0; hh < 4; ++hh) {
        #pragma unroll
        for (int k = 0; k < 4; ++k)
            sq[w * 4096 + hh * 256 + l * 4 + k] = cc[hh][k];
    }
    if (l < 4) { sM[w][l] = m; sSg[w][l] = sg; }   // lane l holds head h=l (ln==0)
    __syncthreads();

    // ---- attn_out: lane (ln,h) finalizes its own row's weight ---------------
    {
        float M = sM[0][h];
        #pragma unroll
        for (int w2 = 1; w2 < 8; ++w2) M = fmaxf(M, sM[w2][h]);
        float S = 0.f;
        #pragma unroll
        for (int w2 = 0; w2 < 8; ++w2) S += sSg[w2][h] * __expf(sM[w2][h] - M);
        float p = ev * __expf(m - M) / S;
        attn_out[(size_t)b * (NH * NN) + h * NN + rr] = p;
    }

    // ---- final c: 512 threads x 2 outputs, merge 8 wave partials ------------
    #pragma unroll
    for (int rep = 0; rep < 2; ++rep) {
        int idx = t + rep * 512;
        int hh = idx >> 8, j = idx & 255;
        float M = sM[0][hh];
        #pragma unroll
        for (int w2 = 1; w2 < 8; ++w2) M = fmaxf(M, sM[w2][hh]);
        float S = 0.f, acc = 0.f;
        #pragma unroll
        for (int w2 = 0; w2 < 8; ++w2) {
            float sc = __expf(sM[w2][hh] - M);
            S   += sSg[w2][hh] * sc;
            acc += sq[w2 * 4096 + hh * 256 + j] * sc;
        }
        c[(size_t)b * 1024 + idx] = acc / S;
    }
}

// ---- kernel 3: v-proj + fc + residual + LN + fc1(relu) + fc2 ---------------
// grid 256, block 256, 8 rows per block (best VALU amortization; round-0 form)
__global__ __launch_bounds__(256) void mlp_kernel(
    const float* __restrict__ c, const float* __restrict__ src,
    const ushort16* __restrict__ wbf,
    const float* __restrict__ fcb, const float* __restrict__ lng,
    const float* __restrict__ lnb, const float* __restrict__ fc1b,
    const float* __restrict__ fc2b, float* __restrict__ zout)
{
    __shared__ float sC[8][1024];   // pooled c rows (32 KB)
    __shared__ float sA[8][256];    // attention out rows
    __shared__ float sX[8][256];    // normalized x
    __shared__ float sS[8][256];    // src rows
    __shared__ float sH[8][256];    // relu(fc1) rows
    __shared__ float sRed[4][8][2]; // [wave][row][{sum, sumsq}]

    const int t  = threadIdx.x;
    const int b0 = blockIdx.x * 8;
    const int h  = t >> 6;          // head for stage A (uniform per wave)

    #pragma unroll
    for (int i = 0; i < 8; ++i)
        *(float4*)&sC[i][t * 4] = *(const float4*)&c[(size_t)(b0 + i) * 1024 + t * 4];
    #pragma unroll
    for (int r = 0; r < 8; ++r) sS[r][t] = src[(size_t)(b0 + r) * DM + t];
    __syncthreads();

    // stage A: out_attn[r][t] = dot(c[r][h*256 + :], wvs[t*256 + :])
    {
        float acc[8] = {0.f,0.f,0.f,0.f,0.f,0.f,0.f,0.f};
        const ushort16* wr = wbf + WOFF_VS + (size_t)t * DM;
        for (int kc = 0; kc < DM; kc += 8) {
            uint4 w8 = *(const uint4*)(wr + kc);
            float wf[8]; unpack8(w8, wf);
            #pragma unroll
            for (int r = 0; r < 8; ++r) acc[r] = dot8(&sC[r][h * 256 + kc], wf, acc[r]);
        }
        #pragma unroll
        for (int r = 0; r < 8; ++r) sA[r][t] = acc[r];
    }
    __syncthreads();

    // stage B: x = out_attn @ fcw^T + fcb + src ; then LayerNorm
    float xv[8];
    {
        float acc[8] = {0.f,0.f,0.f,0.f,0.f,0.f,0.f,0.f};
        const ushort16* wr = wbf + WOFF_FC + (size_t)t * DM;
        for (int kc = 0; kc < DM; kc += 8) {
            uint4 w8 = *(const uint4*)(wr + kc);
            float wf[8]; unpack8(w8, wf);
            #pragma unroll
            for (int r = 0; r < 8; ++r) acc[r] = dot8(&sA[r][kc], wf, acc[r]);
        }
        float bb = fcb[t];
        #pragma unroll
        for (int r = 0; r < 8; ++r) xv[r] = acc[r] + bb + sS[r][t];
    }
    {
        const int w = t >> 6, l = t & 63;
        #pragma unroll
        for (int r = 0; r < 8; ++r) {
            float vs = xv[r], vq = xv[r] * xv[r];
            #pragma unroll
            for (int o = 32; o > 0; o >>= 1) {
                vs += __shfl_xor(vs, o, 64);
                vq += __shfl_xor(vq, o, 64);
            }
            if (l == 0) { sRed[w][r][0] = vs; sRed[w][r][1] = vq; }
        }
        __syncthreads();
        float g = lng[t], bb = lnb[t];
        #pragma unroll
        for (int r = 0; r < 8; ++r) {
            float S = sRed[0][r][0] + sRed[1][r][0] + sRed[2][r][0] + sRed[3][r][0];
            float Q = sRed[0][r][1] + sRed[1][r][1] + sRed[2][r][1] + sRed[3][r][1];
            float mu  = S * (1.f / 256.f);
            float var = Q * (1.f / 256.f) - mu * mu;
            float rs  = rsqrtf(var + 1e-5f);
            sX[r][t] = (xv[r] - mu) * rs * g + bb;
        }
    }
    __syncthreads();

    // stage C: h1 = relu([x | src] @ fc1w^T + fc1b)
    {
        float acc[8] = {0.f,0.f,0.f,0.f,0.f,0.f,0.f,0.f};
        const ushort16* wr = wbf + WOFF_FC1 + (size_t)t * 512;
        for (int kc = 0; kc < 256; kc += 8) {
            uint4 w8 = *(const uint4*)(wr + kc);
            float wf[8]; unpack8(w8, wf);
            #pragma unroll
            for (int r = 0; r < 8; ++r) acc[r] = dot8(&sX[r][kc], wf, acc[r]);
        }
        for (int kc = 0; kc < 256; kc += 8) {
            uint4 w8 = *(const uint4*)(wr + 256 + kc);
            float wf[8]; unpack8(w8, wf);
            #pragma unroll
            for (int r = 0; r < 8; ++r) acc[r] = dot8(&sS[r][kc], wf, acc[r]);
        }
        float bb = fc1b[t];
        #pragma unroll
        for (int r = 0; r < 8; ++r) sH[r][t] = fmaxf(acc[r] + bb, 0.f);
    }
    __syncthreads();

    // stage D: z = h1 @ fc2w^T + fc2b
    {
        float acc[8] = {0.f,0.f,0.f,0.f,0.f,0.f,0.f,0.f};
        const ushort16* wr = wbf + WOFF_FC2 + (size_t)t * DM;
        for (int kc = 0; kc < DM; kc += 8) {
            uint4 w8 = *(const uint4*)(wr + kc);
            float wf[8]; unpack8(w8, wf);
            #pragma unroll
            for (int r = 0; r < 8; ++r) acc[r] = dot8(&sH[r][kc], wf, acc[r]);
        }
        float bb = fc2b[t];
        #pragma unroll
        for (int r = 0; r < 8; ++r)
            zout[(size_t)(b0 + r) * DM + t] = acc[r] + bb;
    }
}

// ---- launch ----------------------------------------------------------------
extern "C" void kernel_launch(void* const* d_in, const int* in_sizes, int n_in,
                              void* d_out, int out_size, void* d_ws, size_t ws_size,
                              hipStream_t stream)
{
    const float* src  = (const float*)d_in[0];
    const float* seq  = (const float*)d_in[1];
    const int*   mask = (const int*)d_in[2];
    const float* wqs  = (const float*)d_in[3];
    const float* wks  = (const float*)d_in[4];
    const float* wvs  = (const float*)d_in[5];
    const float* fcw  = (const float*)d_in[6];
    const float* fcb  = (const float*)d_in[7];
    const float* lng  = (const float*)d_in[8];
    const float* lnb  = (const float*)d_in[9];
    const float* fc1w = (const float*)d_in[10];
    const float* fc1b = (const float*)d_in[11];
    const float* fc2w = (const float*)d_in[12];
    const float* fc2b = (const float*)d_in[13];

    float* zout     = (float*)d_out;
    float* attn_out = zout + (size_t)BATCH * DM;      // z first, then attn

    float* u = (float*)d_ws;                          // 2048*1024 f32 = 8 MB
    float* cbuf = u + (size_t)BATCH * 1024;           // 2048*1024 f32 = 8 MB
    ushort16* wbf = (ushort16*)(cbuf + (size_t)BATCH * 1024);  // 458752 bf16

    prep_kernel<<<448, 256, 0, stream>>>(wqs, wks, wvs, fcw, fc1w, fc2w, wbf);
    qu_kernel<<<512, 256, 0, stream>>>(src, wbf, u);
    attn_kernel<<<BATCH, 512, 0, stream>>>(seq, mask, u, cbuf, attn_out);
    mlp_kernel<<<256, 256, 0, stream>>>(cbuf, src, wbf, fcb, lng, lnb,
                                        fc1b, fc2b, zout);
}